// Round 4
// baseline (289.879 us; speedup 1.0000x reference)
//
#include <hip/hip_runtime.h>

typedef unsigned int uint32;
typedef unsigned long long uint64;

#define BLOCK 256
#define IPT 16                  // rows per thread
#define CHUNK (BLOCK * IPT)     // 4096 rows per block
#define RPI 512                 // rows per iteration (2 per thread)
#define SCORE_THR 0.35f

#define FLAG_AGG 1ull
#define FLAG_PRE 2ull

// state word: [63:62]=flag, [45:23]=v1, [22:0]=v0  (max value 2^22 fits)
__device__ inline uint64 pack_state(uint64 flag, uint32 v0, uint32 v1) {
    return (flag << 62) | ((uint64)v1 << 23) | (uint64)v0;
}

// zero floats [lo, hi) of p, block-local striding, float4 body
__device__ inline void zero_span(float* p, long long lo, long long hi, int tid) {
    long long n = hi - lo;
    if (n <= 0) return;
    float* q = p + lo;
    long long head = (4 - (((size_t)q >> 2) & 3)) & 3;
    if (head > n) head = n;
    if (tid < head) q[tid] = 0.0f;
    long long n4 = (n - head) >> 2;
    float4* b4 = (float4*)(q + head);
    float4 z = make_float4(0.f, 0.f, 0.f, 0.f);
    for (long long k = tid; k < n4; k += BLOCK) b4[k] = z;
    long long done = head + (n4 << 2);
    if (tid < n - done) q[done + tid] = 0.0f;
}

__global__ void __launch_bounds__(BLOCK)
fused_kernel(const float* __restrict__ det,
             float* __restrict__ rois, float* __restrict__ roisf,
             uint64* state, uint32* ticket,
             float* __restrict__ out_n, int R, int NB) {
    int tid = threadIdx.x;
    int wave = tid >> 6, lane = tid & 63;

    __shared__ uint32 sh_bid;
    __shared__ uint32 sh_e[2];
    __shared__ uint32 red0[4], red1[4];
    __shared__ uint32 wc0[2][4], wc1[2][4];
    __shared__ float st0[2][RPI * 5];   // 20 KB
    __shared__ float st1[2][RPI * 6];   // 24 KB

    // virtual block id in scheduling order (deadlock-free lookback)
    if (tid == 0) sh_bid = atomicAdd(ticket, 1u);
    __syncthreads();
    int bid = (int)sh_bid;

    long long base = (long long)bid * CHUNK;
    int rows = (int)min((long long)CHUNK, (long long)R - base);
    bool full = (rows == CHUNK);
    const float4* d4 = (const float4*)(det + base * 6);

    // ---- Phase A: local count (HBM read, once) ----
    uint32 cnt0 = 0, cnt1 = 0;
    if (full) {
        for (int it = 0; it < IPT / 2; ++it) {
            const float4* p = d4 + (long long)it * (BLOCK * 3) + 3 * tid;
            float4 f0 = p[0], f1 = p[1], f2 = p[2];
            bool mA1 = (f1.y >= SCORE_THR);
            bool mA0 = mA1 && (f0.x == 0.0f);
            bool mB1 = (f2.w >= SCORE_THR);
            bool mB0 = mB1 && (f1.z == 0.0f);
            cnt1 += (mA1 ? 1u : 0u) + (mB1 ? 1u : 0u);
            cnt0 += (mA0 ? 1u : 0u) + (mB0 ? 1u : 0u);
        }
    } else {
        for (int i = 0; i < IPT; ++i) {
            int r = i * BLOCK + tid;
            if (r < rows) {
                const float* pp = det + (base + r) * 6;
                bool m1 = (pp[5] >= SCORE_THR);
                bool m0 = m1 && (pp[0] == 0.0f);
                cnt1 += m1 ? 1u : 0u;
                cnt0 += m0 ? 1u : 0u;
            }
        }
    }
    for (int off = 32; off; off >>= 1) {
        cnt0 += __shfl_down(cnt0, off, 64);
        cnt1 += __shfl_down(cnt1, off, 64);
    }
    if (lane == 0) { red0[wave] = cnt0; red1[wave] = cnt1; }
    __syncthreads();
    uint32 a0 = red0[0] + red0[1] + red0[2] + red0[3];
    uint32 a1 = red1[0] + red1[1] + red1[2] + red1[3];

    // publish aggregate (flag+payload in one atomic word — no fence needed)
    if (tid == 0 && bid > 0)
        atomicExch(&state[bid], pack_state(FLAG_AGG, a0, a1));

    // ---- decoupled lookback (wave 0) ----
    if (wave == 0) {
        uint32 e0 = 0, e1 = 0;
        if (bid > 0) {
            int wb = bid;
            while (true) {
                int idx = wb - 1 - lane;
                uint64 s = (idx >= 0) ? atomicAdd(&state[idx], 0ull)
                                      : pack_state(FLAG_PRE, 0u, 0u);
                uint32 flag = (uint32)(s >> 62);
                uint64 pre_mask  = __ballot(flag == 2u);
                uint64 nrdy_mask = __ballot(flag == 0u);
                int pl = pre_mask ? (int)(__ffsll(pre_mask) - 1) : 64;
                uint64 below = (pl >= 64) ? ~0ull : ((1ull << pl) - 1ull);
                if ((nrdy_mask & below) == 0ull) {
                    uint32 v0 = (uint32)(s & 0x7FFFFFu);
                    uint32 v1 = (uint32)((s >> 23) & 0x7FFFFFu);
                    if (lane > pl) { v0 = 0; v1 = 0; }
                    for (int off = 32; off; off >>= 1) {
                        v0 += __shfl_xor(v0, off, 64);
                        v1 += __shfl_xor(v1, off, 64);
                    }
                    e0 += v0; e1 += v1;
                    if (pl < 64) break;
                    wb -= 64;
                } else {
                    __builtin_amdgcn_s_sleep(1);
                }
            }
        }
        if (lane == 0) {
            uint32 i0 = e0 + a0, i1 = e1 + a1;
            atomicExch(&state[bid], pack_state(FLAG_PRE, i0, i1));
            sh_e[0] = e0; sh_e[1] = e1;
            if (bid == NB - 1) { out_n[0] = (float)i0; out_n[1] = (float)i1; }
        }
    }
    __syncthreads();
    uint32 e0s = sh_e[0], e1s = sh_e[1];
    uint32 run0 = e0s, run1 = e1s;
    uint64 ltmask = (1ull << lane) - 1ull;

    // ---- Phase B: stable scatter via LDS staging (L2-hot re-read) ----
    if (full) {
        for (int it = 0; it < IPT / 2; ++it) {
            int buf = it & 1;
            const float4* p = d4 + (long long)it * (BLOCK * 3) + 3 * tid;
            float4 f0 = p[0], f1 = p[1], f2 = p[2];
            // row A = {f0.x,f0.y,f0.z,f0.w,f1.x,f1.y}, row B = {f1.z,f1.w,f2.x,f2.y,f2.z,f2.w}
            bool mA1 = (f1.y >= SCORE_THR);
            bool mA0 = mA1 && (f0.x == 0.0f);
            bool mB1 = (f2.w >= SCORE_THR);
            bool mB0 = mB1 && (f1.z == 0.0f);

            uint64 bA0 = __ballot(mA0), bA1 = __ballot(mA1);
            uint64 bB0 = __ballot(mB0), bB1 = __ballot(mB1);

            if (lane == 0) {
                wc0[buf][wave] = (uint32)(__popcll(bA0) + __popcll(bB0));
                wc1[buf][wave] = (uint32)(__popcll(bA1) + __popcll(bB1));
            }
            __syncthreads();   // counts ready
            uint32 wp0 = 0, wp1 = 0, bt0 = 0, bt1 = 0;
            for (int w = 0; w < 4; ++w) {
                uint32 a = wc0[buf][w], b = wc1[buf][w];
                bt0 += a; bt1 += b;
                if (w < wave) { wp0 += a; wp1 += b; }
            }
            uint32 lA0 = wp0 + (uint32)(__popcll(bA0 & ltmask) + __popcll(bB0 & ltmask));
            uint32 lB0 = lA0 + (mA0 ? 1u : 0u);
            uint32 lA1 = wp1 + (uint32)(__popcll(bA1 & ltmask) + __popcll(bB1 & ltmask));
            uint32 lB1 = lA1 + (mA1 ? 1u : 0u);

            if (mA0) {
                float* s = &st0[buf][lA0 * 5];
                s[0] = 0.0f; s[1] = f0.y; s[2] = f0.z; s[3] = f0.w; s[4] = f1.x;
            }
            if (mB0) {
                float* s = &st0[buf][lB0 * 5];
                s[0] = 0.0f; s[1] = f1.w; s[2] = f2.x; s[3] = f2.y; s[4] = f2.z;
            }
            if (mA1) {
                float* s = &st1[buf][lA1 * 6];
                s[0] = f0.x; s[1] = f0.y; s[2] = f0.z; s[3] = f0.w; s[4] = f1.x; s[5] = f1.y;
            }
            if (mB1) {
                float* s = &st1[buf][lB1 * 6];
                s[0] = f1.z; s[1] = f1.w; s[2] = f2.x; s[3] = f2.y; s[4] = f2.z; s[5] = f2.w;
            }
            __syncthreads();   // staging complete

            uint32 N0 = bt0 * 5, N1 = bt1 * 6;
            float* g0 = rois + (long long)run0 * 5;
            float* g1 = roisf + (long long)run1 * 6;
            for (uint32 j = tid; j < N0; j += BLOCK) g0[j] = st0[buf][j];
            for (uint32 j = tid; j < N1; j += BLOCK) g1[j] = st1[buf][j];
            run0 += bt0; run1 += bt1;
        }
    } else {
        for (int i = 0; i < IPT; ++i) {
            int r = i * BLOCK + tid;
            bool m0 = false, m1 = false;
            float d0 = 0, d1 = 0, d2 = 0, d3 = 0, d4v = 0, d5 = 0;
            if (r < rows) {
                const float* pp = det + (base + r) * 6;
                d0 = pp[0]; d1 = pp[1]; d2 = pp[2]; d3 = pp[3]; d4v = pp[4]; d5 = pp[5];
                m1 = (d5 >= SCORE_THR);
                m0 = m1 && (d0 == 0.0f);
            }
            uint64 b0 = __ballot(m0), b1 = __ballot(m1);
            int buf = i & 1;
            if (lane == 0) {
                wc0[buf][wave] = (uint32)__popcll(b0);
                wc1[buf][wave] = (uint32)__popcll(b1);
            }
            __syncthreads();
            uint32 wp0 = 0, wp1 = 0, bt0 = 0, bt1 = 0;
            for (int w = 0; w < 4; ++w) {
                uint32 a = wc0[buf][w], b = wc1[buf][w];
                bt0 += a; bt1 += b;
                if (w < wave) { wp0 += a; wp1 += b; }
            }
            if (m0) {
                uint32 pos = run0 + wp0 + (uint32)__popcll(b0 & ltmask);
                float* q = rois + (long long)pos * 5;
                q[0] = 0.0f; q[1] = d1; q[2] = d2; q[3] = d3; q[4] = d4v;
            }
            if (m1) {
                uint32 pos = run1 + wp1 + (uint32)__popcll(b1 & ltmask);
                float* q = roisf + (long long)pos * 6;
                q[0] = d0; q[1] = d1; q[2] = d2; q[3] = d3; q[4] = d4v; q[5] = d5;
            }
            run0 += bt0; run1 += bt1;
            __syncthreads();
        }
    }

    // ---- Phase C: zero this block's dropped slots, packed from the END ----
    // dropped-before-me D = base - e; my span is [R - D - d, R - D) rows.
    {
        long long D = base - (long long)e0s;
        long long hi = (long long)R - D;
        long long lo = hi - ((long long)rows - (long long)a0);
        zero_span(rois, lo * 5, hi * 5, tid);
    }
    {
        long long D = base - (long long)e1s;
        long long hi = (long long)R - D;
        long long lo = hi - ((long long)rows - (long long)a1);
        zero_span(roisf, lo * 6, hi * 6, tid);
    }
}

extern "C" void kernel_launch(void* const* d_in, const int* in_sizes, int n_in,
                              void* d_out, int out_size, void* d_ws, size_t ws_size,
                              hipStream_t stream) {
    const float* det = (const float*)d_in[0];
    float* out = (float*)d_out;
    int R = in_sizes[0] / 6;
    int NB = (R + CHUNK - 1) / CHUNK;

    uint64* state = (uint64*)d_ws;              // NB words
    uint32* ticket = (uint32*)(state + NB);     // 1 word

    float* rois  = out;                          // (R,5)
    float* roisf = out + (long long)R * 5;       // (R,6)
    float* nout  = out + (long long)R * 11;      // n, n_full

    hipMemsetAsync(d_ws, 0, (size_t)(NB + 1) * 8, stream);
    fused_kernel<<<NB, BLOCK, 0, stream>>>(det, rois, roisf, state, ticket,
                                           nout, R, NB);
}